// Round 7
// baseline (283.516 us; speedup 1.0000x reference)
//
#include <hip/hip_runtime.h>
#include <hip/hip_bf16.h>

#define NB 8
#define CIN 256
#define LL 4096
#define CQ 32
#define CV 256

typedef __attribute__((ext_vector_type(8))) short bf16x8;
typedef __attribute__((ext_vector_type(4))) float f32x4;

__device__ __forceinline__ unsigned short f2bf(float f) {
    union { __hip_bfloat16 h; unsigned short u; } c;
    c.h = __float2bfloat16(f);
    return c.u;
}
__device__ __forceinline__ float bf2f(unsigned short h) {
    return __uint_as_float(((unsigned)h) << 16);
}

// ---------------- K0: cast weights to bf16; Wq pre-scaled by log2(e) -----------
__global__ __launch_bounds__(256) void k_wcast(
    const float* __restrict__ Wq, const float* __restrict__ Wk,
    const float* __restrict__ Wv, const float* __restrict__ Wo,
    unsigned short* __restrict__ Wb, unsigned short* __restrict__ Wob)
{
    const float LOG2E = 1.4426950408889634f;
    const int row = blockIdx.x, t = threadIdx.x;
    if (row < 320) {
        float val;
        if (row < 32)      val = Wq[row * 256 + t] * LOG2E;
        else if (row < 64) val = Wk[(row - 32) * 256 + t];
        else               val = Wv[(row - 64) * 256 + t];
        Wb[row * 256 + t] = f2bf(val);
    } else {
        const int r2 = row - 320;
        Wob[r2 * 256 + t] = f2bf(Wo[r2 * 256 + t]);
    }
}

// ---------------- K1: fused QKV projection, MFMA bf16, 8 waves -----------------
__global__ __launch_bounds__(512) void k_qkv3(
    const float* __restrict__ x, const unsigned short* __restrict__ Wb,
    unsigned short* __restrict__ qkt, unsigned short* __restrict__ v)
{
    __shared__ unsigned short xlds[64][264];
    __shared__ unsigned short tr[64][72];
    const int n = blockIdx.y, l0 = blockIdx.x * 64, t = threadIdx.x;
    const int w = t >> 6, lane = t & 63, lid = lane & 15, quad = lane >> 4;

    #pragma unroll
    for (int part = 0; part < 4; part++) {
        const int cbase = part * 64 + w * 8;
        float tmp[8];
        #pragma unroll
        for (int cc = 0; cc < 8; cc++)
            tmp[cc] = x[((size_t)n * CIN + cbase + cc) * LL + l0 + lane];
        bf16x8 s;
        #pragma unroll
        for (int cc = 0; cc < 8; cc++) s[cc] = (short)f2bf(tmp[cc]);
        *(bf16x8*)&xlds[lane][cbase] = s;
    }
    __syncthreads();

    const f32x4 fzero = {0.f, 0.f, 0.f, 0.f};
    f32x4 acc[3][4];
    #pragma unroll
    for (int mt = 0; mt < 3; mt++)
        #pragma unroll
        for (int nt = 0; nt < 4; nt++) acc[mt][nt] = fzero;

    for (int k0 = 0; k0 < 256; k0 += 32) {
        bf16x8 bx[4];
        #pragma unroll
        for (int nt = 0; nt < 4; nt++)
            bx[nt] = *(const bf16x8*)&xlds[nt * 16 + lid][k0 + quad * 8];
        #pragma unroll
        for (int vt = 0; vt < 2; vt++) {
            const bf16x8 wa = *(const bf16x8*)&Wb[(64 + w * 32 + vt * 16 + lid) * 256 + k0 + quad * 8];
            #pragma unroll
            for (int nt = 0; nt < 4; nt++)
                acc[vt][nt] = __builtin_amdgcn_mfma_f32_16x16x32_bf16(wa, bx[nt], acc[vt][nt], 0, 0, 0);
        }
        if (w < 4) {
            const bf16x8 wa = *(const bf16x8*)&Wb[(w * 16 + lid) * 256 + k0 + quad * 8];
            #pragma unroll
            for (int nt = 0; nt < 4; nt++)
                acc[2][nt] = __builtin_amdgcn_mfma_f32_16x16x32_bf16(wa, bx[nt], acc[2][nt], 0, 0, 0);
        }
    }
    #pragma unroll
    for (int vt = 0; vt < 2; vt++)
        #pragma unroll
        for (int nt = 0; nt < 4; nt++)
            #pragma unroll
            for (int reg = 0; reg < 4; reg++) {
                const int vr = w * 32 + vt * 16 + quad * 4 + reg;
                v[((size_t)n * CV + vr) * LL + l0 + nt * 16 + lid] = f2bf(acc[vt][nt][reg]);
            }
    if (w < 4) {
        #pragma unroll
        for (int nt = 0; nt < 4; nt++)
            #pragma unroll
            for (int reg = 0; reg < 4; reg++)
                tr[nt * 16 + lid][w * 16 + quad * 4 + reg] = f2bf(acc[2][nt][reg]);
    }
    __syncthreads();
    {
        const int l = t >> 3, c = (t & 7) * 8;
        *(uint4*)&qkt[((size_t)n * LL + l0 + l) * 64 + c] = *(const uint4*)&tr[l][c];
    }
}

// ---------------- K2: lns[i] = -log2( sum_j 2^(e2_ij) ), 8 waves ---------------
__global__ __launch_bounds__(512) void k_rowsum3(
    const unsigned short* __restrict__ qkt, float* __restrict__ lns)
{
    __shared__ float red[64];
    const int n = blockIdx.y, i0 = blockIdx.x * 64, t = threadIdx.x;
    const int w = t >> 6, lid = t & 15, quad = (t & 63) >> 4;
    if (t < 64) red[t] = 0.f;
    __syncthreads();

    bf16x8 aq[4];
    #pragma unroll
    for (int mt = 0; mt < 4; mt++)
        aq[mt] = *(const bf16x8*)&qkt[((size_t)n * LL + i0 + mt * 16 + lid) * 64 + quad * 8];

    const f32x4 fzero = {0.f, 0.f, 0.f, 0.f};
    float sums[4][4];
    #pragma unroll
    for (int mt = 0; mt < 4; mt++)
        #pragma unroll
        for (int reg = 0; reg < 4; reg++) sums[mt][reg] = 0.f;

    for (int jt = 0; jt < 8; jt++) {
        const int j0 = jt * 512 + w * 64;
        bf16x8 bk[4];
        #pragma unroll
        for (int nt = 0; nt < 4; nt++)
            bk[nt] = *(const bf16x8*)&qkt[((size_t)n * LL + j0 + nt * 16 + lid) * 64 + 32 + quad * 8];
        #pragma unroll
        for (int mt = 0; mt < 4; mt++)
            #pragma unroll
            for (int nt = 0; nt < 4; nt++) {
                f32x4 e = __builtin_amdgcn_mfma_f32_16x16x32_bf16(aq[mt], bk[nt], fzero, 0, 0, 0);
                sums[mt][0] += __builtin_amdgcn_exp2f(e[0]);
                sums[mt][1] += __builtin_amdgcn_exp2f(e[1]);
                sums[mt][2] += __builtin_amdgcn_exp2f(e[2]);
                sums[mt][3] += __builtin_amdgcn_exp2f(e[3]);
            }
    }
    #pragma unroll
    for (int mt = 0; mt < 4; mt++)
        #pragma unroll
        for (int reg = 0; reg < 4; reg++) {
            float s = sums[mt][reg];
            s += __shfl_xor(s, 1); s += __shfl_xor(s, 2);
            s += __shfl_xor(s, 4); s += __shfl_xor(s, 8);
            if (lid == 0) atomicAdd(&red[mt * 16 + quad * 4 + reg], s);
        }
    __syncthreads();
    if (t < 64) lns[(size_t)n * LL + i0 + t] = -__builtin_log2f(red[t]);
}

// ---------------- K3: fused attention core + output projection ----------------
// grid (512), 512 thr (8 waves). n = bid&7, j-tile 64 = bid>>3. i-chunk 128/iter.
// Wave w: E-rows [w*16, w*16+16); V-rows [(w&3)*64, +64) over i-half g=w>>2.
// P stored in MFMA-frag order: pbuf[buf][nt][kb][lane][8] -> reads are
// wave-uniform-base + lane*16 (canonical conflict-free b128).
// Waves (w, w+4) hold partial O over i-halves; combined via LDS at the end.
__global__ __launch_bounds__(512, 4) void k_attn7(
    const unsigned short* __restrict__ qkt, const unsigned short* __restrict__ v,
    const float* __restrict__ lns, const unsigned short* __restrict__ Wob,
    const float* __restrict__ gp, float* __restrict__ out)
{
    __shared__ unsigned short pbuf[2][4][4][64][8];  // 32 KB
    __shared__ unsigned short olds[64][264];         // 33792 B
    unsigned short* cbuf = &pbuf[0][0][0][0][0];     // epilogue alias, 32 KB

    const int bid = blockIdx.x;
    const int n = bid & 7, j0 = (bid >> 3) * 64, t = threadIdx.x;
    const int w = t >> 6, lane = t & 63, lid = lane & 15, quad = lane >> 4;
    const int g = w >> 2, wl = w & 3;
    const int kbw = w >> 1;                     // E-write kb block
    const int qr = (w & 1) * 2 + (quad >> 1);   // E-write k-octet within kb
    const int e0 = (quad & 1) * 4;              // E-write elem offset

    const unsigned short* qrow = qkt + ((size_t)n * LL + w * 16 + lid) * 64 + quad * 8;
    const float* lrow = lns + (size_t)n * LL + w * 16 + quad * 4;
    const unsigned short* vbase = v + ((size_t)n * CV + wl * 64 + lid) * LL + g * 64 + quad * 8;

    bf16x8 bk[4];
    #pragma unroll
    for (int nt = 0; nt < 4; nt++)
        bk[nt] = *(const bf16x8*)&qkt[((size_t)n * LL + j0 + nt * 16 + lid) * 64 + 32 + quad * 8];

    const f32x4 fzero = {0.f, 0.f, 0.f, 0.f};
    f32x4 acc[4][4];
    #pragma unroll
    for (int mt = 0; mt < 4; mt++)
        #pragma unroll
        for (int nt = 0; nt < 4; nt++) acc[mt][nt] = fzero;

    // ---- prologue: E(0) -> pbuf[0]; prefetch aq/lns(1); av for (ic=0,h=0) ----
    bf16x8 aq = *(const bf16x8*)qrow;
    f32x4 lnsC = *(const f32x4*)lrow;
    {
        f32x4 e[4];
        #pragma unroll
        for (int nt = 0; nt < 4; nt++)
            e[nt] = __builtin_amdgcn_mfma_f32_16x16x32_bf16(aq, bk[nt], lnsC, 0, 0, 0);
        aq = *(const bf16x8*)(qrow + (size_t)128 * 64);
        lnsC = *(const f32x4*)(lrow + 128);
        #pragma unroll
        for (int nt = 0; nt < 4; nt++) {
            ushort4 s;
            s.x = f2bf(__builtin_amdgcn_exp2f(e[nt][0]));
            s.y = f2bf(__builtin_amdgcn_exp2f(e[nt][1]));
            s.z = f2bf(__builtin_amdgcn_exp2f(e[nt][2]));
            s.w = f2bf(__builtin_amdgcn_exp2f(e[nt][3]));
            *(ushort4*)&pbuf[0][nt][kbw][qr * 16 + lid][e0] = s;
        }
    }
    bf16x8 av[4];
    #pragma unroll
    for (int mt = 0; mt < 4; mt++)
        av[mt] = *(const bf16x8*)(vbase + (size_t)mt * 16 * LL);
    __syncthreads();

    for (int ic = 0; ic < 31; ic++) {
        const int cur = ic & 1;
        const size_t i0 = (size_t)ic * 128;
        // E for ic+1
        f32x4 e2[4];
        #pragma unroll
        for (int nt = 0; nt < 4; nt++)
            e2[nt] = __builtin_amdgcn_mfma_f32_16x16x32_bf16(aq, bk[nt], lnsC, 0, 0, 0);
        const size_t ipf = (ic < 30) ? (i0 + 256) : i0;
        aq = *(const bf16x8*)(qrow + ipf * 64);
        lnsC = *(const f32x4*)(lrow + ipf);
        #pragma unroll
        for (int nt = 0; nt < 4; nt++) {
            ushort4 s;
            s.x = f2bf(__builtin_amdgcn_exp2f(e2[nt][0]));
            s.y = f2bf(__builtin_amdgcn_exp2f(e2[nt][1]));
            s.z = f2bf(__builtin_amdgcn_exp2f(e2[nt][2]));
            s.w = f2bf(__builtin_amdgcn_exp2f(e2[nt][3]));
            *(ushort4*)&pbuf[cur ^ 1][nt][kbw][qr * 16 + lid][e0] = s;
        }
        // O-phase, h = 0 (kb = 2g)
        {
            bf16x8 bp[4];
            #pragma unroll
            for (int nt = 0; nt < 4; nt++)
                bp[nt] = *(const bf16x8*)&pbuf[cur][nt][2 * g][lane][0];
            #pragma unroll
            for (int mt = 0; mt < 4; mt++)
                #pragma unroll
                for (int nt = 0; nt < 4; nt++)
                    acc[mt][nt] = __builtin_amdgcn_mfma_f32_16x16x32_bf16(av[mt], bp[nt], acc[mt][nt], 0, 0, 0);
            #pragma unroll
            for (int mt = 0; mt < 4; mt++)   // av for h=1 (in-place)
                av[mt] = *(const bf16x8*)(vbase + (size_t)mt * 16 * LL + i0 + 32);
        }
        // O-phase, h = 1 (kb = 2g+1)
        {
            bf16x8 bp[4];
            #pragma unroll
            for (int nt = 0; nt < 4; nt++)
                bp[nt] = *(const bf16x8*)&pbuf[cur][nt][2 * g + 1][lane][0];
            #pragma unroll
            for (int mt = 0; mt < 4; mt++)
                #pragma unroll
                for (int nt = 0; nt < 4; nt++)
                    acc[mt][nt] = __builtin_amdgcn_mfma_f32_16x16x32_bf16(av[mt], bp[nt], acc[mt][nt], 0, 0, 0);
            #pragma unroll
            for (int mt = 0; mt < 4; mt++)   // av for next iter h=0 (in-place)
                av[mt] = *(const bf16x8*)(vbase + (size_t)mt * 16 * LL + i0 + 128);
        }
        __syncthreads();
    }
    // ---- final iter ic=31 (buf 1), no reload past the end ----
    {
        const size_t i0 = (size_t)31 * 128;
        {
            bf16x8 bp[4];
            #pragma unroll
            for (int nt = 0; nt < 4; nt++)
                bp[nt] = *(const bf16x8*)&pbuf[1][nt][2 * g][lane][0];
            #pragma unroll
            for (int mt = 0; mt < 4; mt++)
                #pragma unroll
                for (int nt = 0; nt < 4; nt++)
                    acc[mt][nt] = __builtin_amdgcn_mfma_f32_16x16x32_bf16(av[mt], bp[nt], acc[mt][nt], 0, 0, 0);
            #pragma unroll
            for (int mt = 0; mt < 4; mt++)
                av[mt] = *(const bf16x8*)(vbase + (size_t)mt * 16 * LL + i0 + 32);
        }
        {
            bf16x8 bp[4];
            #pragma unroll
            for (int nt = 0; nt < 4; nt++)
                bp[nt] = *(const bf16x8*)&pbuf[1][nt][2 * g + 1][lane][0];
            #pragma unroll
            for (int mt = 0; mt < 4; mt++)
                #pragma unroll
                for (int nt = 0; nt < 4; nt++)
                    acc[mt][nt] = __builtin_amdgcn_mfma_f32_16x16x32_bf16(av[mt], bp[nt], acc[mt][nt], 0, 0, 0);
        }
    }
    __syncthreads();   // all P reads done; pbuf reusable as cbuf

    // ---- combine partial O: waves 4-7 -> LDS (bf16), waves 0-3 add ----
    if (g == 1) {
        #pragma unroll
        for (int mt = 0; mt < 4; mt++)
            #pragma unroll
            for (int nt = 0; nt < 4; nt++) {
                ushort4 s;
                s.x = f2bf(acc[mt][nt][0]); s.y = f2bf(acc[mt][nt][1]);
                s.z = f2bf(acc[mt][nt][2]); s.w = f2bf(acc[mt][nt][3]);
                *(ushort4*)&cbuf[(((wl * 4 + mt) * 4 + nt) * 64 + lane) * 4] = s;
            }
    }
    __syncthreads();
    if (g == 0) {
        #pragma unroll
        for (int mt = 0; mt < 4; mt++)
            #pragma unroll
            for (int nt = 0; nt < 4; nt++) {
                const ushort4 p = *(const ushort4*)&cbuf[(((wl * 4 + mt) * 4 + nt) * 64 + lane) * 4];
                ushort4 s;
                s.x = f2bf(acc[mt][nt][0] + bf2f(p.x));
                s.y = f2bf(acc[mt][nt][1] + bf2f(p.y));
                s.z = f2bf(acc[mt][nt][2] + bf2f(p.z));
                s.w = f2bf(acc[mt][nt][3] + bf2f(p.w));
                *(ushort4*)&olds[nt * 16 + lid][wl * 64 + mt * 16 + quad * 4] = s;
            }
    }
    __syncthreads();

    // ---- Wo GEMM: all 8 waves, out rows [w*32, w*32+32) x 64 l ----
    f32x4 oacc[2][4];
    #pragma unroll
    for (int mt = 0; mt < 2; mt++)
        #pragma unroll
        for (int nt = 0; nt < 4; nt++) oacc[mt][nt] = fzero;
    for (int k0 = 0; k0 < 256; k0 += 32) {
        bf16x8 bo[4];
        #pragma unroll
        for (int nt = 0; nt < 4; nt++)
            bo[nt] = *(const bf16x8*)&olds[nt * 16 + lid][k0 + quad * 8];
        #pragma unroll
        for (int mt = 0; mt < 2; mt++) {
            const bf16x8 wa = *(const bf16x8*)&Wob[(w * 32 + mt * 16 + lid) * 256 + k0 + quad * 8];
            #pragma unroll
            for (int nt = 0; nt < 4; nt++)
                oacc[mt][nt] = __builtin_amdgcn_mfma_f32_16x16x32_bf16(wa, bo[nt], oacc[mt][nt], 0, 0, 0);
        }
    }
    const float gm = *gp;
    #pragma unroll
    for (int mt = 0; mt < 2; mt++)
        #pragma unroll
        for (int nt = 0; nt < 4; nt++)
            #pragma unroll
            for (int reg = 0; reg < 4; reg++) {
                const int r = w * 32 + mt * 16 + quad * 4 + reg;
                out[((size_t)n * CIN + r) * LL + j0 + nt * 16 + lid] = gm * oacc[mt][nt][reg];
            }
}

extern "C" void kernel_launch(void* const* d_in, const int* in_sizes, int n_in,
                              void* d_out, int out_size, void* d_ws, size_t ws_size,
                              hipStream_t stream) {
    const float* x     = (const float*)d_in[0];
    const float* Wq    = (const float*)d_in[1];
    const float* Wk    = (const float*)d_in[2];
    const float* Wv    = (const float*)d_in[3];
    const float* Wo    = (const float*)d_in[4];
    const float* gamma = (const float*)d_in[5];

    unsigned short* qkt = (unsigned short*)d_ws;              // 4 MB
    unsigned short* v   = qkt + (size_t)NB * LL * 64;         // 16 MB
    unsigned short* Wb  = v + (size_t)NB * CV * LL;           // 160 KB
    unsigned short* Wob = Wb + 320 * 256;                     // 128 KB
    float* lns          = (float*)(Wob + 256 * 256);          // 128 KB
    float* out = (float*)d_out;

    k_wcast  <<<dim3(576),   256, 0, stream>>>(Wq, Wk, Wv, Wo, Wb, Wob);
    k_qkv3   <<<dim3(64, 8), 512, 0, stream>>>(x, Wb, qkt, v);
    k_rowsum3<<<dim3(64, 8), 512, 0, stream>>>(qkt, lns);
    k_attn7  <<<dim3(512),   512, 0, stream>>>(qkt, v, lns, Wob, gamma, out);
}

// Round 8
// 265.541 us; speedup vs baseline: 1.0677x; 1.0677x over previous
//
#include <hip/hip_runtime.h>
#include <hip/hip_bf16.h>

#define NB 8
#define CIN 256
#define LL 4096
#define CQ 32
#define CV 256

typedef __attribute__((ext_vector_type(8))) short bf16x8;
typedef __attribute__((ext_vector_type(4))) float f32x4;

__device__ __forceinline__ unsigned short f2bf(float f) {
    union { __hip_bfloat16 h; unsigned short u; } c;
    c.h = __float2bfloat16(f);
    return c.u;
}
__device__ __forceinline__ float bf2f(unsigned short h) {
    return __uint_as_float(((unsigned)h) << 16);
}

// ---------------- K0: cast weights to bf16; Wq pre-scaled by log2(e) -----------
__global__ __launch_bounds__(256) void k_wcast(
    const float* __restrict__ Wq, const float* __restrict__ Wk,
    const float* __restrict__ Wv, const float* __restrict__ Wo,
    unsigned short* __restrict__ Wb, unsigned short* __restrict__ Wob)
{
    const float LOG2E = 1.4426950408889634f;
    const int row = blockIdx.x, t = threadIdx.x;
    if (row < 320) {
        float val;
        if (row < 32)      val = Wq[row * 256 + t] * LOG2E;
        else if (row < 64) val = Wk[(row - 32) * 256 + t];
        else               val = Wv[(row - 64) * 256 + t];
        Wb[row * 256 + t] = f2bf(val);
    } else {
        const int r2 = row - 320;
        Wob[r2 * 256 + t] = f2bf(Wo[r2 * 256 + t]);
    }
}

// ---------------- K1: fused QKV projection, MFMA bf16, 8 waves -----------------
__global__ __launch_bounds__(512) void k_qkv3(
    const float* __restrict__ x, const unsigned short* __restrict__ Wb,
    unsigned short* __restrict__ qkt, unsigned short* __restrict__ v)
{
    __shared__ unsigned short xlds[64][264];
    __shared__ unsigned short tr[64][72];
    const int n = blockIdx.y, l0 = blockIdx.x * 64, t = threadIdx.x;
    const int w = t >> 6, lane = t & 63, lid = lane & 15, quad = lane >> 4;

    #pragma unroll
    for (int part = 0; part < 4; part++) {
        const int cbase = part * 64 + w * 8;
        float tmp[8];
        #pragma unroll
        for (int cc = 0; cc < 8; cc++)
            tmp[cc] = x[((size_t)n * CIN + cbase + cc) * LL + l0 + lane];
        bf16x8 s;
        #pragma unroll
        for (int cc = 0; cc < 8; cc++) s[cc] = (short)f2bf(tmp[cc]);
        *(bf16x8*)&xlds[lane][cbase] = s;
    }
    __syncthreads();

    const f32x4 fzero = {0.f, 0.f, 0.f, 0.f};
    f32x4 acc[3][4];
    #pragma unroll
    for (int mt = 0; mt < 3; mt++)
        #pragma unroll
        for (int nt = 0; nt < 4; nt++) acc[mt][nt] = fzero;

    for (int k0 = 0; k0 < 256; k0 += 32) {
        bf16x8 bx[4];
        #pragma unroll
        for (int nt = 0; nt < 4; nt++)
            bx[nt] = *(const bf16x8*)&xlds[nt * 16 + lid][k0 + quad * 8];
        #pragma unroll
        for (int vt = 0; vt < 2; vt++) {
            const bf16x8 wa = *(const bf16x8*)&Wb[(64 + w * 32 + vt * 16 + lid) * 256 + k0 + quad * 8];
            #pragma unroll
            for (int nt = 0; nt < 4; nt++)
                acc[vt][nt] = __builtin_amdgcn_mfma_f32_16x16x32_bf16(wa, bx[nt], acc[vt][nt], 0, 0, 0);
        }
        if (w < 4) {
            const bf16x8 wa = *(const bf16x8*)&Wb[(w * 16 + lid) * 256 + k0 + quad * 8];
            #pragma unroll
            for (int nt = 0; nt < 4; nt++)
                acc[2][nt] = __builtin_amdgcn_mfma_f32_16x16x32_bf16(wa, bx[nt], acc[2][nt], 0, 0, 0);
        }
    }
    #pragma unroll
    for (int vt = 0; vt < 2; vt++)
        #pragma unroll
        for (int nt = 0; nt < 4; nt++)
            #pragma unroll
            for (int reg = 0; reg < 4; reg++) {
                const int vr = w * 32 + vt * 16 + quad * 4 + reg;
                v[((size_t)n * CV + vr) * LL + l0 + nt * 16 + lid] = f2bf(acc[vt][nt][reg]);
            }
    if (w < 4) {
        #pragma unroll
        for (int nt = 0; nt < 4; nt++)
            #pragma unroll
            for (int reg = 0; reg < 4; reg++)
                tr[nt * 16 + lid][w * 16 + quad * 4 + reg] = f2bf(acc[2][nt][reg]);
    }
    __syncthreads();
    {
        const int l = t >> 3, c = (t & 7) * 8;
        *(uint4*)&qkt[((size_t)n * LL + l0 + l) * 64 + c] = *(const uint4*)&tr[l][c];
    }
}

// ---------------- K2: lns[i] = -log2( sum_j 2^(e2_ij) ), 8 waves ---------------
__global__ __launch_bounds__(512) void k_rowsum3(
    const unsigned short* __restrict__ qkt, float* __restrict__ lns)
{
    __shared__ float red[64];
    const int n = blockIdx.y, i0 = blockIdx.x * 64, t = threadIdx.x;
    const int w = t >> 6, lid = t & 15, quad = (t & 63) >> 4;
    if (t < 64) red[t] = 0.f;
    __syncthreads();

    bf16x8 aq[4];
    #pragma unroll
    for (int mt = 0; mt < 4; mt++)
        aq[mt] = *(const bf16x8*)&qkt[((size_t)n * LL + i0 + mt * 16 + lid) * 64 + quad * 8];

    const f32x4 fzero = {0.f, 0.f, 0.f, 0.f};
    float sums[4][4];
    #pragma unroll
    for (int mt = 0; mt < 4; mt++)
        #pragma unroll
        for (int reg = 0; reg < 4; reg++) sums[mt][reg] = 0.f;

    for (int jt = 0; jt < 8; jt++) {
        const int j0 = jt * 512 + w * 64;
        bf16x8 bk[4];
        #pragma unroll
        for (int nt = 0; nt < 4; nt++)
            bk[nt] = *(const bf16x8*)&qkt[((size_t)n * LL + j0 + nt * 16 + lid) * 64 + 32 + quad * 8];
        #pragma unroll
        for (int mt = 0; mt < 4; mt++)
            #pragma unroll
            for (int nt = 0; nt < 4; nt++) {
                f32x4 e = __builtin_amdgcn_mfma_f32_16x16x32_bf16(aq[mt], bk[nt], fzero, 0, 0, 0);
                sums[mt][0] += __builtin_amdgcn_exp2f(e[0]);
                sums[mt][1] += __builtin_amdgcn_exp2f(e[1]);
                sums[mt][2] += __builtin_amdgcn_exp2f(e[2]);
                sums[mt][3] += __builtin_amdgcn_exp2f(e[3]);
            }
    }
    #pragma unroll
    for (int mt = 0; mt < 4; mt++)
        #pragma unroll
        for (int reg = 0; reg < 4; reg++) {
            float s = sums[mt][reg];
            s += __shfl_xor(s, 1); s += __shfl_xor(s, 2);
            s += __shfl_xor(s, 4); s += __shfl_xor(s, 8);
            if (lid == 0) atomicAdd(&red[mt * 16 + quad * 4 + reg], s);
        }
    __syncthreads();
    if (t < 64) lns[(size_t)n * LL + i0 + t] = -__builtin_log2f(red[t]);
}

// ---------------- K3: fused attention core + output projection ----------------
// grid (512), 512 thr (8 waves). n = bid&7, j-tile 64 = bid>>3. i-chunk 128/iter.
// k_attn6 register structure (acc[2][4], av[8], no spill) + k_attn7 frag-order
// P layout: pbuf[buf][nt][kb][lane][8] = P[j = nt*16 + (lane&15)]
//                                         [i = kb*32 + (lane>>4)*8 + elem].
// Reads: wave-uniform base + lane*16B b128 (conflict-free). Writes 2-way (free).
__global__ __launch_bounds__(512, 4) void k_attn8(
    const unsigned short* __restrict__ qkt, const unsigned short* __restrict__ v,
    const float* __restrict__ lns, const unsigned short* __restrict__ Wob,
    const float* __restrict__ gp, float* __restrict__ out)
{
    __shared__ unsigned short pbuf[2][4][4][64][8];  // 32 KB
    __shared__ unsigned short olds[64][264];         // 33792 B (epilogue)

    const int bid = blockIdx.x;
    const int n = bid & 7, j0 = (bid >> 3) * 64, t = threadIdx.x;
    const int w = t >> 6, lane = t & 63, lid = lane & 15, quad = lane >> 4;
    const int kbw = w >> 1;                     // E-write kb block
    const int qr = (w & 1) * 2 + (quad >> 1);   // E-write k-octet within kb
    const int e0 = (quad & 1) * 4;              // E-write elem offset

    const unsigned short* qrow = qkt + ((size_t)n * LL + w * 16 + lid) * 64 + quad * 8;
    const float* lrow = lns + (size_t)n * LL + w * 16 + quad * 4;
    const unsigned short* vrow = v + ((size_t)n * CV + w * 32 + lid) * LL + quad * 8;

    bf16x8 bk[4];
    #pragma unroll
    for (int nt = 0; nt < 4; nt++)
        bk[nt] = *(const bf16x8*)&qkt[((size_t)n * LL + j0 + nt * 16 + lid) * 64 + 32 + quad * 8];

    const f32x4 fzero = {0.f, 0.f, 0.f, 0.f};
    f32x4 acc[2][4];
    #pragma unroll
    for (int mt = 0; mt < 2; mt++)
        #pragma unroll
        for (int nt = 0; nt < 4; nt++) acc[mt][nt] = fzero;

    // ---- prologue: E(0) -> pbuf[0]; prefetch aq/lns(1); av(ic=0) ----
    bf16x8 aq = *(const bf16x8*)qrow;
    f32x4 lnsC = *(const f32x4*)lrow;
    {
        f32x4 e[4];
        #pragma unroll
        for (int nt = 0; nt < 4; nt++)
            e[nt] = __builtin_amdgcn_mfma_f32_16x16x32_bf16(aq, bk[nt], lnsC, 0, 0, 0);
        aq = *(const bf16x8*)(qrow + (size_t)128 * 64);
        lnsC = *(const f32x4*)(lrow + 128);
        #pragma unroll
        for (int nt = 0; nt < 4; nt++) {
            ushort4 s;
            s.x = f2bf(__builtin_amdgcn_exp2f(e[nt][0]));
            s.y = f2bf(__builtin_amdgcn_exp2f(e[nt][1]));
            s.z = f2bf(__builtin_amdgcn_exp2f(e[nt][2]));
            s.w = f2bf(__builtin_amdgcn_exp2f(e[nt][3]));
            *(ushort4*)&pbuf[0][nt][kbw][qr * 16 + lid][e0] = s;
        }
    }
    bf16x8 av[8];   // [mt*4+h]
    #pragma unroll
    for (int mt = 0; mt < 2; mt++)
        #pragma unroll
        for (int h = 0; h < 4; h++)
            av[mt * 4 + h] = *(const bf16x8*)(vrow + (size_t)mt * 16 * LL + h * 32);
    __syncthreads();

    for (int ic = 0; ic < 31; ic++) {
        const int cur = ic & 1;
        const size_t i0 = (size_t)ic * 128;
        // E for ic+1 (operands prefetched)
        f32x4 e2[4];
        #pragma unroll
        for (int nt = 0; nt < 4; nt++)
            e2[nt] = __builtin_amdgcn_mfma_f32_16x16x32_bf16(aq, bk[nt], lnsC, 0, 0, 0);
        // prefetch aq/lns for ic+2
        const size_t ipf = (ic < 30) ? (i0 + 256) : i0;
        aq = *(const bf16x8*)(qrow + ipf * 64);
        lnsC = *(const f32x4*)(lrow + ipf);
        // finish E: exp2 + pack + write P(ic+1) — lgkm drains during O-phase
        #pragma unroll
        for (int nt = 0; nt < 4; nt++) {
            ushort4 s;
            s.x = f2bf(__builtin_amdgcn_exp2f(e2[nt][0]));
            s.y = f2bf(__builtin_amdgcn_exp2f(e2[nt][1]));
            s.z = f2bf(__builtin_amdgcn_exp2f(e2[nt][2]));
            s.w = f2bf(__builtin_amdgcn_exp2f(e2[nt][3]));
            *(ushort4*)&pbuf[cur ^ 1][nt][kbw][qr * 16 + lid][e0] = s;
        }
        // O-phase on buf cur; in-place av reload after last use per h
        #pragma unroll
        for (int h = 0; h < 4; h++) {
            bf16x8 bp[4];
            #pragma unroll
            for (int nt = 0; nt < 4; nt++)
                bp[nt] = *(const bf16x8*)&pbuf[cur][nt][h][lane][0];
            #pragma unroll
            for (int mt = 0; mt < 2; mt++)
                #pragma unroll
                for (int nt = 0; nt < 4; nt++)
                    acc[mt][nt] = __builtin_amdgcn_mfma_f32_16x16x32_bf16(av[mt * 4 + h], bp[nt], acc[mt][nt], 0, 0, 0);
            // in-place reload for next iter (WAR on regs already read by MFMA)
            #pragma unroll
            for (int mt = 0; mt < 2; mt++)
                av[mt * 4 + h] = *(const bf16x8*)(vrow + (size_t)mt * 16 * LL + (i0 + 128) + h * 32);
        }
        __syncthreads();
    }
    // ---- final O-phase: ic=31, buf 1 ----
    #pragma unroll
    for (int h = 0; h < 4; h++) {
        bf16x8 bp[4];
        #pragma unroll
        for (int nt = 0; nt < 4; nt++)
            bp[nt] = *(const bf16x8*)&pbuf[1][nt][h][lane][0];
        #pragma unroll
        for (int mt = 0; mt < 2; mt++)
            #pragma unroll
            for (int nt = 0; nt < 4; nt++)
                acc[mt][nt] = __builtin_amdgcn_mfma_f32_16x16x32_bf16(av[mt * 4 + h], bp[nt], acc[mt][nt], 0, 0, 0);
    }
    __syncthreads();   // all P reads done

    // ---- epilogue: o-tile -> olds[j][v] ----
    #pragma unroll
    for (int mt = 0; mt < 2; mt++)
        #pragma unroll
        for (int nt = 0; nt < 4; nt++) {
            ushort4 s;
            s.x = f2bf(acc[mt][nt][0]); s.y = f2bf(acc[mt][nt][1]);
            s.z = f2bf(acc[mt][nt][2]); s.w = f2bf(acc[mt][nt][3]);
            *(ushort4*)&olds[nt * 16 + lid][w * 32 + mt * 16 + quad * 4] = s;
        }
    __syncthreads();
    // out rows [w*32, w*32+32) x 64 l
    f32x4 oacc[2][4];
    #pragma unroll
    for (int mt = 0; mt < 2; mt++)
        #pragma unroll
        for (int nt = 0; nt < 4; nt++) oacc[mt][nt] = fzero;
    for (int k0 = 0; k0 < 256; k0 += 32) {
        bf16x8 bo[4];
        #pragma unroll
        for (int nt = 0; nt < 4; nt++)
            bo[nt] = *(const bf16x8*)&olds[nt * 16 + lid][k0 + quad * 8];
        #pragma unroll
        for (int mt = 0; mt < 2; mt++) {
            const bf16x8 wa = *(const bf16x8*)&Wob[(w * 32 + mt * 16 + lid) * 256 + k0 + quad * 8];
            #pragma unroll
            for (int nt = 0; nt < 4; nt++)
                oacc[mt][nt] = __builtin_amdgcn_mfma_f32_16x16x32_bf16(wa, bo[nt], oacc[mt][nt], 0, 0, 0);
        }
    }
    const float g = *gp;
    #pragma unroll
    for (int mt = 0; mt < 2; mt++)
        #pragma unroll
        for (int nt = 0; nt < 4; nt++)
            #pragma unroll
            for (int reg = 0; reg < 4; reg++) {
                const int r = w * 32 + mt * 16 + quad * 4 + reg;
                out[((size_t)n * CIN + r) * LL + j0 + nt * 16 + lid] = g * oacc[mt][nt][reg];
            }
}

extern "C" void kernel_launch(void* const* d_in, const int* in_sizes, int n_in,
                              void* d_out, int out_size, void* d_ws, size_t ws_size,
                              hipStream_t stream) {
    const float* x     = (const float*)d_in[0];
    const float* Wq    = (const float*)d_in[1];
    const float* Wk    = (const float*)d_in[2];
    const float* Wv    = (const float*)d_in[3];
    const float* Wo    = (const float*)d_in[4];
    const float* gamma = (const float*)d_in[5];

    unsigned short* qkt = (unsigned short*)d_ws;              // 4 MB
    unsigned short* v   = qkt + (size_t)NB * LL * 64;         // 16 MB
    unsigned short* Wb  = v + (size_t)NB * CV * LL;           // 160 KB
    unsigned short* Wob = Wb + 320 * 256;                     // 128 KB
    float* lns          = (float*)(Wob + 256 * 256);          // 128 KB
    float* out = (float*)d_out;

    k_wcast  <<<dim3(576),   256, 0, stream>>>(Wq, Wk, Wv, Wo, Wb, Wob);
    k_qkv3   <<<dim3(64, 8), 512, 0, stream>>>(x, Wb, qkt, v);
    k_rowsum3<<<dim3(64, 8), 512, 0, stream>>>(qkt, lns);
    k_attn8  <<<dim3(512),   512, 0, stream>>>(qkt, v, lns, Wob, gamma, out);
}